// Round 1
// baseline (467.937 us; speedup 1.0000x reference)
//
#include <hip/hip_runtime.h>

// Guided filter, radius=3 (7x7 box, zero-pad conv semantics: always /49),
// fused single kernel. B=8, H=W=1024, p has 3 channels sharing one I channel.
//
// Tile structure per block:
//   output tile : 32x32  at (gy0, gx0)
//   a/b grid    : 38x38  (= tile + 2*R), image rows gy0-3 .. gy0+34
//   input region: 44x44  (= tile + 4*R), image rows gy0-6 .. gy0+37
//
// a,b are forced to 0 at grid positions outside the image (reference box-
// filters the materialized a,b arrays with zero padding).

#define R     3
#define K     7
#define TILE  32
#define AREG  38   // TILE + 2*R
#define IREG  44   // TILE + 4*R
#define IMG_H 1024
#define IMG_W 1024
#define NTHREADS 256

__global__ __launch_bounds__(NTHREADS) void guided_filter_kernel(
    const float* __restrict__ I, const float* __restrict__ P,
    float* __restrict__ Q)
{
    __shared__ float sI [IREG*IREG];  // raw I region
    __shared__ float sP [IREG*IREG];  // raw p region (per channel)
    __shared__ float h1 [IREG*AREG];  // horizontal sums scratch
    __shared__ float h2 [IREG*AREG];
    __shared__ float mI [AREG*AREG];  // mean_I   (persistent across channels)
    __shared__ float mII[AREG*AREG];  // mean_II  (persistent across channels)
    __shared__ float sa [AREG*AREG];  // a
    __shared__ float sb [AREG*AREG];  // b

    const int tiles_x     = IMG_W / TILE;           // 32
    const int tiles_per_b = tiles_x * (IMG_H / TILE); // 1024
    const int b   = blockIdx.x / tiles_per_b;
    const int t   = blockIdx.x % tiles_per_b;
    const int gy0 = (t / tiles_x) * TILE;
    const int gx0 = (t % tiles_x) * TILE;

    const int tid = threadIdx.x;
    const float inv49 = 1.0f / 49.0f;

    const float* Ib = I + (size_t)b * IMG_H * IMG_W;

    // ---- load I region (zero padded) ----
    for (int idx = tid; idx < IREG*IREG; idx += NTHREADS) {
        int iy = idx / IREG, ix = idx % IREG;
        int gy = gy0 - 2*R + iy, gx = gx0 - 2*R + ix;
        float v = 0.f;
        if (gy >= 0 && gy < IMG_H && gx >= 0 && gx < IMG_W)
            v = Ib[gy*IMG_W + gx];
        sI[idx] = v;
    }
    __syncthreads();

    // ---- horizontal 7-tap raw sums of I and I*I ----
    for (int idx = tid; idx < IREG*AREG; idx += NTHREADS) {
        int y = idx / AREG, x = idx % AREG;
        float s = 0.f, s2 = 0.f;
        #pragma unroll
        for (int d = 0; d < K; ++d) {
            float v = sI[y*IREG + x + d];
            s += v; s2 += v*v;
        }
        h1[idx] = s; h2[idx] = s2;
    }
    __syncthreads();

    // ---- vertical -> mean_I, mean_II on 38x38 grid ----
    for (int idx = tid; idx < AREG*AREG; idx += NTHREADS) {
        int y = idx / AREG, x = idx % AREG;
        float s = 0.f, s2 = 0.f;
        #pragma unroll
        for (int d = 0; d < K; ++d) {
            s  += h1[(y+d)*AREG + x];
            s2 += h2[(y+d)*AREG + x];
        }
        mI [idx] = s  * inv49;
        mII[idx] = s2 * inv49;
    }
    __syncthreads();

    for (int c = 0; c < 3; ++c) {
        const float* Pb = P + ((size_t)b*3 + c) * IMG_H * IMG_W;
        float*       Qb = Q + ((size_t)b*3 + c) * IMG_H * IMG_W;

        // ---- load p region (zero padded) ----
        for (int idx = tid; idx < IREG*IREG; idx += NTHREADS) {
            int iy = idx / IREG, ix = idx % IREG;
            int gy = gy0 - 2*R + iy, gx = gx0 - 2*R + ix;
            float v = 0.f;
            if (gy >= 0 && gy < IMG_H && gx >= 0 && gx < IMG_W)
                v = Pb[gy*IMG_W + gx];
            sP[idx] = v;
        }
        __syncthreads();

        // ---- horizontal sums of p and I*p ----
        for (int idx = tid; idx < IREG*AREG; idx += NTHREADS) {
            int y = idx / AREG, x = idx % AREG;
            float s = 0.f, s2 = 0.f;
            #pragma unroll
            for (int d = 0; d < K; ++d) {
                float pv = sP[y*IREG + x + d];
                float iv = sI[y*IREG + x + d];
                s += pv; s2 += iv*pv;
            }
            h1[idx] = s; h2[idx] = s2;
        }
        __syncthreads();

        // ---- vertical -> mean_p, mean_Ip; compute a,b (zero outside image) ----
        for (int idx = tid; idx < AREG*AREG; idx += NTHREADS) {
            int y = idx / AREG, x = idx % AREG;
            float s = 0.f, s2 = 0.f;
            #pragma unroll
            for (int d = 0; d < K; ++d) {
                s  += h1[(y+d)*AREG + x];
                s2 += h2[(y+d)*AREG + x];
            }
            float mp  = s  * inv49;
            float mip = s2 * inv49;
            float mi  = mI[idx], mii = mII[idx];
            float a   = (mip - mi*mp) / ((mii - mi*mi) + 1e-6f);
            float bb  = mp - a*mi;
            int gy = gy0 - R + y, gx = gx0 - R + x;
            if (gy < 0 || gy >= IMG_H || gx < 0 || gx >= IMG_W) { a = 0.f; bb = 0.f; }
            sa[idx] = a; sb[idx] = bb;
        }
        __syncthreads();

        // ---- horizontal sums of a, b : [AREG rows][TILE cols] ----
        for (int idx = tid; idx < AREG*TILE; idx += NTHREADS) {
            int y = idx / TILE, x = idx % TILE;
            float s = 0.f, s2 = 0.f;
            #pragma unroll
            for (int d = 0; d < K; ++d) {
                s  += sa[y*AREG + x + d];
                s2 += sb[y*AREG + x + d];
            }
            h1[idx] = s; h2[idx] = s2;
        }
        __syncthreads();

        // ---- vertical + final combine + clip + store ----
        for (int idx = tid; idx < TILE*TILE; idx += NTHREADS) {
            int y = idx / TILE, x = idx % TILE;
            float s = 0.f, s2 = 0.f;
            #pragma unroll
            for (int d = 0; d < K; ++d) {
                s  += h1[(y+d)*TILE + x];
                s2 += h2[(y+d)*TILE + x];
            }
            float ma = s * inv49, mb = s2 * inv49;
            float q  = ma * sI[(y + 2*R)*IREG + (x + 2*R)] + mb;
            q = fminf(fmaxf(q, 0.f), 1.f);
            Qb[(size_t)(gy0 + y)*IMG_W + (gx0 + x)] = q;
        }
        __syncthreads();  // h1/h2/sP reused by next channel
    }
}

extern "C" void kernel_launch(void* const* d_in, const int* in_sizes, int n_in,
                              void* d_out, int out_size, void* d_ws, size_t ws_size,
                              hipStream_t stream) {
    const float* I = (const float*)d_in[0];
    const float* P = (const float*)d_in[1];
    // d_in[2] = radius (always 3; kernel hardcodes R=3)
    float* Q = (float*)d_out;

    const int blocks = 8 * (IMG_H / TILE) * (IMG_W / TILE); // 8192
    guided_filter_kernel<<<blocks, NTHREADS, 0, stream>>>(I, P, Q);
}

// Round 2
// 430.465 us; speedup vs baseline: 1.0871x; 1.0871x over previous
//
#include <hip/hip_runtime.h>

// Guided filter, radius=3 (7x7 box, zero-pad conv, always /49), fused.
// B=8, H=W=1024, 3 p-channels share one I channel.
//
// R2: all box sums are ROLLING sums (add entering tap, subtract leaving tap)
// -> ~2 LDS reads/output/array instead of 7. LDS strides padded to odd to
// break bank conflicts.
//
// Per block: output tile 32x32; a/b grid 38x38; input region 44x44.

#define R     3
#define TILE  32
#define AREG  38   // TILE + 2*R
#define IREG  44   // TILE + 4*R
#define ISTR  45   // padded stride for sI/sP (44 cols used)
#define HSTR  39   // padded stride for h1/h2/mI/mII/sa/sb (38 cols used)
#define BSTR  33   // stride for ab horizontal results (32 cols used)
#define IMG_H 1024
#define IMG_W 1024
#define NTHREADS 256

__global__ __launch_bounds__(NTHREADS) void guided_filter_kernel(
    const float* __restrict__ I, const float* __restrict__ P,
    float* __restrict__ Q)
{
    __shared__ float sI [IREG*ISTR];  // raw I region           (1980 f)
    __shared__ float sP [IREG*ISTR];  // raw p region            (1980 f)
    __shared__ float h1 [IREG*HSTR];  // horiz sums / ab-horiz   (1716 f)
    __shared__ float h2 [IREG*HSTR];  //                         (1716 f)
    __shared__ float mI [AREG*HSTR];  // mean_I  (persists)      (1482 f)
    __shared__ float mII[AREG*HSTR];  // mean_II (persists)      (1482 f)
    __shared__ float sa [AREG*HSTR];  // a                       (1482 f)
    __shared__ float sb [AREG*HSTR];  // b                       (1482 f)
    // total 13320 floats = 53.3 KB -> 3 blocks/CU

    const int tiles_x     = IMG_W / TILE;             // 32
    const int tiles_per_b = tiles_x * (IMG_H / TILE); // 1024
    const int b   = blockIdx.x / tiles_per_b;
    const int t   = blockIdx.x % tiles_per_b;
    const int gy0 = (t / tiles_x) * TILE;
    const int gx0 = (t % tiles_x) * TILE;

    const int tid = threadIdx.x;
    const float inv49 = 1.0f / 49.0f;

    const float* Ib = I + (size_t)b * IMG_H * IMG_W;

    // ================= I phase =================
    // load I region (zero padded)
    for (int idx = tid; idx < IREG*IREG; idx += NTHREADS) {
        int iy = idx / IREG, ix = idx - iy*IREG;
        int gy = gy0 - 2*R + iy, gx = gx0 - 2*R + ix;
        float v = 0.f;
        if ((unsigned)gy < IMG_H && (unsigned)gx < IMG_W)
            v = Ib[gy*IMG_W + gx];
        sI[iy*ISTR + ix] = v;
    }
    __syncthreads();

    // horizontal rolling sums of I, I*I : 44 rows x 4 segments of 10
    if (tid < IREG*4) {
        int r = tid >> 2, sg = tid & 3;
        int x0 = sg*10, xe = (x0+10 < AREG) ? x0+10 : AREG;
        const float* row = sI + r*ISTR;
        float* o1 = h1 + r*HSTR;
        float* o2 = h2 + r*HSTR;
        float s1 = 0.f, s2 = 0.f;
        #pragma unroll
        for (int i = 0; i < 6; ++i) { float v = row[x0+i]; s1 += v; s2 += v*v; }
        for (int x = x0; x < xe; ++x) {
            float vn = row[x+6], vo = row[x];
            s1 += vn; s2 += vn*vn;
            o1[x] = s1; o2[x] = s2;
            s1 -= vo; s2 -= vo*vo;
        }
    }
    __syncthreads();

    // vertical rolling -> mean_I, mean_II : x in [0,38) x 6 y-segments of 7
    {
        int x  = tid % AREG;
        int sg = tid / AREG;
        if (sg < 6) {
            int y0 = sg*7, ye = (y0+7 < AREG) ? y0+7 : AREG;
            float s1 = 0.f, s2 = 0.f;
            #pragma unroll
            for (int i = 0; i < 6; ++i) {
                s1 += h1[(y0+i)*HSTR + x]; s2 += h2[(y0+i)*HSTR + x];
            }
            for (int y = y0; y < ye; ++y) {
                s1 += h1[(y+6)*HSTR + x]; s2 += h2[(y+6)*HSTR + x];
                mI [y*HSTR + x] = s1 * inv49;
                mII[y*HSTR + x] = s2 * inv49;
                s1 -= h1[y*HSTR + x]; s2 -= h2[y*HSTR + x];
            }
        }
    }
    __syncthreads();

    // ================= channel loop =================
    for (int c = 0; c < 3; ++c) {
        const float* Pb = P + ((size_t)b*3 + c) * IMG_H * IMG_W;
        float*       Qb = Q + ((size_t)b*3 + c) * IMG_H * IMG_W;

        // load p region (zero padded)
        for (int idx = tid; idx < IREG*IREG; idx += NTHREADS) {
            int iy = idx / IREG, ix = idx - iy*IREG;
            int gy = gy0 - 2*R + iy, gx = gx0 - 2*R + ix;
            float v = 0.f;
            if ((unsigned)gy < IMG_H && (unsigned)gx < IMG_W)
                v = Pb[gy*IMG_W + gx];
            sP[iy*ISTR + ix] = v;
        }
        __syncthreads();

        // horizontal rolling sums of p, I*p : 44 rows x 4 segments of 10
        if (tid < IREG*4) {
            int r = tid >> 2, sg = tid & 3;
            int x0 = sg*10, xe = (x0+10 < AREG) ? x0+10 : AREG;
            const float* prow = sP + r*ISTR;
            const float* irow = sI + r*ISTR;
            float* o1 = h1 + r*HSTR;
            float* o2 = h2 + r*HSTR;
            float s1 = 0.f, s2 = 0.f;
            #pragma unroll
            for (int i = 0; i < 6; ++i) {
                float pv = prow[x0+i]; s1 += pv; s2 += irow[x0+i]*pv;
            }
            for (int x = x0; x < xe; ++x) {
                float pn = prow[x+6], po = prow[x];
                s1 += pn;            s2 += irow[x+6]*pn;
                o1[x] = s1; o2[x] = s2;
                s1 -= po;            s2 -= irow[x]*po;
            }
        }
        __syncthreads();

        // vertical rolling -> mean_p, mean_Ip; compute a,b (zero outside img)
        {
            int x  = tid % AREG;
            int sg = tid / AREG;
            if (sg < 6) {
                int y0 = sg*7, ye = (y0+7 < AREG) ? y0+7 : AREG;
                float s1 = 0.f, s2 = 0.f;
                #pragma unroll
                for (int i = 0; i < 6; ++i) {
                    s1 += h1[(y0+i)*HSTR + x]; s2 += h2[(y0+i)*HSTR + x];
                }
                for (int y = y0; y < ye; ++y) {
                    s1 += h1[(y+6)*HSTR + x]; s2 += h2[(y+6)*HSTR + x];
                    float mp  = s1 * inv49;
                    float mip = s2 * inv49;
                    float mi  = mI[y*HSTR + x], mii = mII[y*HSTR + x];
                    float var = (mii - mi*mi) + 1e-6f;
                    float a   = (mip - mi*mp) * __builtin_amdgcn_rcpf(var);
                    float bb  = mp - a*mi;
                    int gy = gy0 - R + y, gx = gx0 - R + x;
                    if ((unsigned)gy >= IMG_H || (unsigned)gx >= IMG_W) { a = 0.f; bb = 0.f; }
                    sa[y*HSTR + x] = a;
                    sb[y*HSTR + x] = bb;
                    s1 -= h1[y*HSTR + x]; s2 -= h2[y*HSTR + x];
                }
            }
        }
        __syncthreads();

        // horizontal rolling sums of a,b : 38 rows x 4 segments of 8 (exact)
        if (tid < AREG*4) {
            int r = tid >> 2, sg = tid & 3;
            int x0 = sg*8;
            const float* ra = sa + r*HSTR;
            const float* rb = sb + r*HSTR;
            float* o1 = h1 + r*BSTR;
            float* o2 = h2 + r*BSTR;
            float s1 = 0.f, s2 = 0.f;
            #pragma unroll
            for (int i = 0; i < 6; ++i) { s1 += ra[x0+i]; s2 += rb[x0+i]; }
            #pragma unroll
            for (int x = x0; x < x0+8; ++x) {
                s1 += ra[x+6]; s2 += rb[x+6];
                o1[x] = s1; o2[x] = s2;
                s1 -= ra[x]; s2 -= rb[x];
            }
        }
        __syncthreads();

        // final vertical rolling + combine + clip + store : 32 x 8 segs of 4
        {
            int x  = tid & 31;
            int sg = tid >> 5;          // 0..7
            int y0 = sg*4;
            float s1 = 0.f, s2 = 0.f;
            #pragma unroll
            for (int i = 0; i < 6; ++i) {
                s1 += h1[(y0+i)*BSTR + x]; s2 += h2[(y0+i)*BSTR + x];
            }
            #pragma unroll
            for (int y = y0; y < y0+4; ++y) {
                s1 += h1[(y+6)*BSTR + x]; s2 += h2[(y+6)*BSTR + x];
                float ma = s1 * inv49, mb = s2 * inv49;
                float q  = ma * sI[(y + 2*R)*ISTR + (x + 2*R)] + mb;
                q = fminf(fmaxf(q, 0.f), 1.f);
                Qb[(size_t)(gy0 + y)*IMG_W + (gx0 + x)] = q;
                s1 -= h1[y*BSTR + x]; s2 -= h2[y*BSTR + x];
            }
        }
        __syncthreads();  // h1/h2/sP reused by next channel
    }
}

extern "C" void kernel_launch(void* const* d_in, const int* in_sizes, int n_in,
                              void* d_out, int out_size, void* d_ws, size_t ws_size,
                              hipStream_t stream) {
    const float* I = (const float*)d_in[0];
    const float* P = (const float*)d_in[1];
    // d_in[2] = radius (always 3; kernel hardcodes R=3)
    float* Q = (float*)d_out;

    const int blocks = 8 * (IMG_H / TILE) * (IMG_W / TILE); // 8192
    guided_filter_kernel<<<blocks, NTHREADS, 0, stream>>>(I, P, Q);
}

// Round 3
// 391.234 us; speedup vs baseline: 1.1961x; 1.1003x over previous
//
#include <hip/hip_runtime.h>

// Guided filter r=3 (7x7 box, zero-pad /49), fused streaming kernel.
// Thread = image column. Block = 128 threads = 128 input columns
// (116 output cols). Block sweeps 80 rows of a 64-row segment.
// All vertical box sums are rolling register updates; horizontal sums are
// 7-tap LDS reads from per-row ring buffers. Pipeline lags: ab row = y-3
// (held 1 half-iter), stage-2 horiz at row y-7, output row o = y-10.
// One barrier per 4 rows; ring depth 8 makes all slots statically disjoint.

#define TPB   128
#define OUTW  116
#define SEGH  64
#define HW    1024
#define GW    134          // TPB + 6 guard cells for taps
#define EPSF  1e-6f
#define INV49 (1.0f/49.0f)

struct GFState {
    // stage-1 colsums + h-history rings (depth 8, static idx)
    float csI, csII, csp0, csp1, csp2, csq0, csq1, csq2;
    float hrI[8], hrII[8], hrp0[8], hrp1[8], hrp2[8], hrq0[8], hrq1[8], hrq2[8];
    // stage-2 colsums + s2h-history rings
    float c2a0, c2b0, c2a1, c2b1, c2a2, c2b2;
    float h2a0[8], h2b0[8], h2a1[8], h2b1[8], h2a2[8], h2b2[8];
    // ab rows computed this half, written next half
    float ha[4][3], hb[4][3];
    // staged raw rows (to write at next half) + I at upcoming output rows
    float4 cur[4];
    float  Iq[4], IqN[4];
};

template<int JB>
__device__ __forceinline__ void halfStep(
    GFState& S, int j0, int Y0, int x_in, bool xok, int xc, int tid,
    const float* __restrict__ Ip, const float* __restrict__ P0,
    const float* __restrict__ P1, const float* __restrict__ P2,
    float* __restrict__ Q0, float* __restrict__ Q1, float* __restrict__ Q2,
    float4 (*rawbuf)[GW], float4 (*abA)[GW], float2 (*abB)[GW],
    bool dostore, bool dopref)
{
    // ---- write phase: raw rows j0..j0+3 (slots JB+u), ab rows j0-7..j0-4
    // (slots JB+u+1). Disjoint mod 8 from the other half's read slots.
    #pragma unroll
    for (int u = 0; u < 4; ++u) {
        rawbuf[(JB+u)&7][tid+3] = S.cur[u];
        const int w = (JB+u+1)&7;
        abA[w][tid+3] = make_float4(S.ha[u][0], S.hb[u][0], S.ha[u][1], S.hb[u][1]);
        abB[w][tid+3] = make_float2(S.ha[u][2], S.hb[u][2]);
    }
    __syncthreads();

    // ---- prefetch rows j0+4..j0+7 and I at output rows (j0+4..j0+7)-10
    if (dopref) {
        #pragma unroll
        for (int u = 0; u < 4; ++u) {
            int y = Y0 + j0 + 4 + u;
            bool ok = xok && ((unsigned)y < HW);
            int yy = min(max(y, 0), HW-1);
            size_t off = (size_t)yy*HW + xc;
            float a0 = Ip[off], a1 = P0[off], a2 = P1[off], a3 = P2[off];
            float4 v;
            v.x = ok ? a0 : 0.f; v.y = ok ? a1 : 0.f;
            v.z = ok ? a2 : 0.f; v.w = ok ? a3 : 0.f;
            S.cur[u] = v;
        }
        #pragma unroll
        for (int u = 0; u < 4; ++u) {
            int o = Y0 + j0 - 6 + u;
            bool ok = xok && ((unsigned)o < HW);
            int oo = min(max(o, 0), HW-1);
            float v = Ip[(size_t)oo*HW + xc];
            S.IqN[u] = ok ? v : 0.f;
        }
    }

    // ---- process rows j = j0..j0+3
    #pragma unroll
    for (int u = 0; u < 4; ++u) {
        const int slot  = (JB+u)&7;     // raw row j; h(j) store
        const int slotw = (JB+u+1)&7;   // h(j-7) sub; ab row j-7; s2h store
        const int slot2 = (JB+u+2)&7;   // s2h(j-14) sub
        const int y = Y0 + j0 + u;

        // stage-1 horizontal 7-tap on raw row j
        float hI=0,hII=0,hp0=0,hp1=0,hp2=0,hq0=0,hq1=0,hq2=0;
        #pragma unroll
        for (int d = 0; d < 7; ++d) {
            float4 t = rawbuf[slot][tid+d];
            hI  += t.x; hII = fmaf(t.x, t.x, hII);
            hp0 += t.y; hq0 = fmaf(t.x, t.y, hq0);
            hp1 += t.z; hq1 = fmaf(t.x, t.z, hq1);
            hp2 += t.w; hq2 = fmaf(t.x, t.w, hq2);
        }
        // stage-1 vertical rolling colsums
        S.csI  += hI  - S.hrI [slotw]; S.hrI [slot] = hI;
        S.csII += hII - S.hrII[slotw]; S.hrII[slot] = hII;
        S.csp0 += hp0 - S.hrp0[slotw]; S.hrp0[slot] = hp0;
        S.csp1 += hp1 - S.hrp1[slotw]; S.hrp1[slot] = hp1;
        S.csp2 += hp2 - S.hrp2[slotw]; S.hrp2[slot] = hp2;
        S.csq0 += hq0 - S.hrq0[slotw]; S.hrq0[slot] = hq0;
        S.csq1 += hq1 - S.hrq1[slotw]; S.hrq1[slot] = hq1;
        S.csq2 += hq2 - S.hrq2[slotw]; S.hrq2[slot] = hq2;

        // a,b at image row y-3 (zero outside image; matches zero-pad of a,b)
        {
            float mi_ = S.csI*INV49, mii = S.csII*INV49;
            float rv  = __builtin_amdgcn_rcpf(mii - mi_*mi_ + EPSF);
            bool abok = xok && ((unsigned)(y-3) < HW);
            float mp, mq, a, b;
            mp = S.csp0*INV49; mq = S.csq0*INV49;
            a = (mq - mi_*mp)*rv; b = fmaf(-a, mi_, mp);
            S.ha[u][0] = abok ? a : 0.f; S.hb[u][0] = abok ? b : 0.f;
            mp = S.csp1*INV49; mq = S.csq1*INV49;
            a = (mq - mi_*mp)*rv; b = fmaf(-a, mi_, mp);
            S.ha[u][1] = abok ? a : 0.f; S.hb[u][1] = abok ? b : 0.f;
            mp = S.csp2*INV49; mq = S.csq2*INV49;
            a = (mq - mi_*mp)*rv; b = fmaf(-a, mi_, mp);
            S.ha[u][2] = abok ? a : 0.f; S.hb[u][2] = abok ? b : 0.f;
        }

        // stage-2 horizontal 7-tap on ab row j-7
        float sa0=0,sb0=0,sa1=0,sb1=0,sa2=0,sb2=0;
        #pragma unroll
        for (int d = 0; d < 7; ++d) {
            float4 A = abA[slotw][tid+d];
            float2 B = abB[slotw][tid+d];
            sa0 += A.x; sb0 += A.y; sa1 += A.z; sb1 += A.w;
            sa2 += B.x; sb2 += B.y;
        }
        // stage-2 vertical rolling colsums
        S.c2a0 += sa0 - S.h2a0[slot2]; S.h2a0[slotw] = sa0;
        S.c2b0 += sb0 - S.h2b0[slot2]; S.h2b0[slotw] = sb0;
        S.c2a1 += sa1 - S.h2a1[slot2]; S.h2a1[slotw] = sa1;
        S.c2b1 += sb1 - S.h2b1[slot2]; S.h2b1[slotw] = sb1;
        S.c2a2 += sa2 - S.h2a2[slot2]; S.h2a2[slotw] = sa2;
        S.c2b2 += sb2 - S.h2b2[slot2]; S.h2b2[slotw] = sb2;

        // output row o = y-10
        if (dostore) {
            int o = y - 10;
            float Io = S.Iq[u];
            bool sok = (tid >= 6) && (tid < 122) && (x_in < HW);
            size_t ooff = (size_t)o*HW + x_in;
            float q;
            q = fmaf(S.c2a0*INV49, Io, S.c2b0*INV49);
            q = fminf(fmaxf(q, 0.f), 1.f); if (sok) Q0[ooff] = q;
            q = fmaf(S.c2a1*INV49, Io, S.c2b1*INV49);
            q = fminf(fmaxf(q, 0.f), 1.f); if (sok) Q1[ooff] = q;
            q = fmaf(S.c2a2*INV49, Io, S.c2b2*INV49);
            q = fminf(fmaxf(q, 0.f), 1.f); if (sok) Q2[ooff] = q;
        }
    }

    #pragma unroll
    for (int u = 0; u < 4; ++u) S.Iq[u] = S.IqN[u];
}

__global__ __launch_bounds__(TPB, 2) void gf_kernel(
    const float* __restrict__ I, const float* __restrict__ P,
    float* __restrict__ Q)
{
    __shared__ float4 rawbuf[8][GW];
    __shared__ float4 abA[8][GW];
    __shared__ float2 abB[8][GW];

    const int s   = blockIdx.x;      // x-stripe (9)
    const int seg = blockIdx.y;      // y-segment (16)
    const int b   = blockIdx.z;      // batch (8)
    const int tid = threadIdx.x;

    const int X0   = s*OUTW - 6;
    const int Y0   = seg*SEGH - 6;
    const int x_in = X0 + tid;
    const bool xok = (unsigned)x_in < HW;
    const int  xc  = min(max(x_in, 0), HW-1);

    const float* Ip = I + (size_t)b*HW*HW;
    const float* P0 = P + ((size_t)b*3 + 0)*HW*HW;
    const float* P1 = P + ((size_t)b*3 + 1)*HW*HW;
    const float* P2 = P + ((size_t)b*3 + 2)*HW*HW;
    float* Q0 = Q + ((size_t)b*3 + 0)*HW*HW;
    float* Q1 = Q + ((size_t)b*3 + 1)*HW*HW;
    float* Q2 = Q + ((size_t)b*3 + 2)*HW*HW;

    GFState S;
    S.csI=S.csII=S.csp0=S.csp1=S.csp2=S.csq0=S.csq1=S.csq2=0.f;
    S.c2a0=S.c2b0=S.c2a1=S.c2b1=S.c2a2=S.c2b2=0.f;
    #pragma unroll
    for (int i = 0; i < 8; ++i) {
        S.hrI[i]=S.hrII[i]=S.hrp0[i]=S.hrp1[i]=S.hrp2[i]=0.f;
        S.hrq0[i]=S.hrq1[i]=S.hrq2[i]=0.f;
        S.h2a0[i]=S.h2b0[i]=S.h2a1[i]=S.h2b1[i]=S.h2a2[i]=S.h2b2[i]=0.f;
    }
    #pragma unroll
    for (int u = 0; u < 4; ++u) {
        S.ha[u][0]=S.ha[u][1]=S.ha[u][2]=0.f;
        S.hb[u][0]=S.hb[u][1]=S.hb[u][2]=0.f;
        S.Iq[u]=S.IqN[u]=0.f;
    }
    // preload rows 0..3
    #pragma unroll
    for (int u = 0; u < 4; ++u) {
        int y = Y0 + u;
        bool ok = xok && ((unsigned)y < HW);
        int yy = min(max(y, 0), HW-1);
        size_t off = (size_t)yy*HW + xc;
        float a0 = Ip[off], a1 = P0[off], a2 = P1[off], a3 = P2[off];
        float4 v;
        v.x = ok ? a0 : 0.f; v.y = ok ? a1 : 0.f;
        v.z = ok ? a2 : 0.f; v.w = ok ? a3 : 0.f;
        S.cur[u] = v;
    }

    for (int m = 0; m < 10; ++m) {
        int j0 = m*8;
        halfStep<0>(S, j0,   Y0, x_in, xok, xc, tid, Ip, P0, P1, P2,
                    Q0, Q1, Q2, rawbuf, abA, abB,
                    (j0   >= 16), true);
        halfStep<4>(S, j0+4, Y0, x_in, xok, xc, tid, Ip, P0, P1, P2,
                    Q0, Q1, Q2, rawbuf, abA, abB,
                    (j0+4 >= 16), (j0+4) < 76);
    }
}

extern "C" void kernel_launch(void* const* d_in, const int* in_sizes, int n_in,
                              void* d_out, int out_size, void* d_ws, size_t ws_size,
                              hipStream_t stream) {
    const float* I = (const float*)d_in[0];
    const float* P = (const float*)d_in[1];
    // d_in[2] = radius (always 3; hardcoded)
    float* Q = (float*)d_out;

    dim3 grid(9, 16, 8);   // x-stripes, y-segments, batch
    gf_kernel<<<grid, TPB, 0, stream>>>(I, P, Q);
}